// Round 5
// baseline (297.423 us; speedup 1.0000x reference)
//
#include <hip/hip_runtime.h>
#include <math.h>

#define Dd 128
#define Hh 4
#define DKk 32
#define Mm 5
#define NNn 15
#define Bb 1024
#define Nn 64
#define MN 75
#define BN 65536
#define RSQRT_DK 0.17677669529663687f

typedef __attribute__((ext_vector_type(8))) short bf16x8;
typedef __attribute__((ext_vector_type(4))) float f32x4;

__device__ __forceinline__ ushort f2bf(float x) {
    unsigned u = __float_as_uint(x);
    u = (u + 0x7fffu + ((u >> 16) & 1u)) >> 16;
    return (ushort)u;
}
__device__ __forceinline__ float bf2f(ushort h) {
    return __uint_as_float(((unsigned)h) << 16);
}
__device__ __forceinline__ void split2(float x, ushort& hi, ushort& lo) {
    hi = f2bf(x);
    lo = f2bf(x - bf2f(hi));
}
__device__ __forceinline__ f32x4 MFMA(bf16x8 a, bf16x8 b, f32x4 c) {
    return __builtin_amdgcn_mfma_f32_16x16x32_bf16(a, b, c, 0, 0, 0);
}

// ---------------------------------------------------------------------------
// k0: weight preprocessing (tiny, runs every call). Unchanged from round 4.
// ---------------------------------------------------------------------------
__global__ void k0_prep(const float* __restrict__ maskm,
                        const float* __restrict__ WK, const float* __restrict__ bK,
                        const float* __restrict__ WQ, const float* __restrict__ bQ,
                        const float* __restrict__ WM, const float* __restrict__ bM,
                        const float* __restrict__ WB, const float* __restrict__ bB,
                        const float* __restrict__ Wu, const float* __restrict__ Wd,
                        const float* __restrict__ Wl, const float* __restrict__ Wr,
                        ushort* __restrict__ WKhi, ushort* __restrict__ WKlo,
                        ushort* __restrict__ WQhi, ushort* __restrict__ WQlo,
                        ushort* __restrict__ WMhi, ushort* __restrict__ WBhi,
                        ushort* __restrict__ maskhi, ushort* __restrict__ masklo,
                        ushort* __restrict__ maskThi, ushort* __restrict__ maskTlo,
                        float* __restrict__ btK, float* __restrict__ btQ,
                        float* __restrict__ btM, float* __restrict__ btB,
                        ushort* __restrict__ WcatT)
{
    int tid = blockIdx.x * blockDim.x + threadIdx.x;
    int nthr = gridDim.x * blockDim.x;
    const int NW = Mm * Dd * Dd;  // 81920
    for (int i = tid; i < NW; i += nthr) {
        split2(WK[i], WKhi[i], WKlo[i]);
        split2(WQ[i], WQhi[i], WQlo[i]);
        WMhi[i] = f2bf(WM[i]);
        WBhi[i] = f2bf(WB[i]);
    }
    for (int i = tid; i < 96 * 64; i += nthr) {
        float v = (i < MN * 64) ? maskm[i] : 0.f;
        split2(v, maskhi[i], masklo[i]);
    }
    for (int i = tid; i < 64 * 96; i += nthr) {
        int col = i / 96, j = i - col * 96;
        float v = (j < MN) ? maskm[j * 64 + col] : 0.f;
        split2(v, maskThi[i], maskTlo[i]);
    }
    for (int i = tid; i < 4096; i += nthr) {
        int q = i >> 5, kk = i & 31;
        const float* Wsel = (q < 32) ? Wu : (q < 64) ? Wd : (q < 96) ? Wl : Wr;
        WcatT[i] = f2bf(Wsel[kk * 32 + (q & 31)]);
    }
    for (int i = tid; i < 8192; i += nthr) {
        int d = i >> 6, col = i & 63;
        float aKv = 0.f, aQv = 0.f, aBv = 0.f;
        for (int m = 0; m < Mm; ++m) {
            float mrs = 0.f;
            for (int N = 0; N < NNn; ++N) mrs += maskm[(m * 15 + N) * 64 + col];
            aKv += bK[m * 128 + d] * mrs;
            aQv += bQ[m * 128 + d] * mrs;
            aBv += bB[m * 128 + d] * mrs;
        }
        btK[i] = aKv; btQ[i] = aQv; btB[i] = aBv;
        float aMv = 0.f;
        int dd = d;
        for (int j = 0; j < MN; ++j) {
            int f = dd * 75 + j;
            int m = f / 1920;
            int dloc = (f / 15) & 127;
            aMv += bM[m * 128 + dloc] * maskm[j * 64 + col];
        }
        btM[i] = aMv;
    }
}

// ---------------------------------------------------------------------------
// k1 v5: fused K+Q phases, register WW staging, quarter-tiled Y planes.
//   phase0: nimT[m*16+N][e] split (node A-frags hoisted; WW direct from global)
//   4 quarters (32 d-rows): Y-phase (K+Q merged, nimT frag reuse) -> mask-phase
//   msg: Y flat-scatter phase + mask phase (planes reused as xM[128][104])
// LDS 70,144 B -> 2 blocks/CU; 11 barriers (was ~17).
// ---------------------------------------------------------------------------
__global__ __launch_bounds__(512, 4) void k1_proj(
    const float* __restrict__ node, const float* __restrict__ WW,
    const ushort* __restrict__ WKhi, const ushort* __restrict__ WKlo,
    const ushort* __restrict__ WQhi, const ushort* __restrict__ WQlo,
    const ushort* __restrict__ WMhi,
    const ushort* __restrict__ maskThi, const ushort* __restrict__ maskTlo,
    const float* __restrict__ btK, const float* __restrict__ btQ,
    const float* __restrict__ btM,
    float* __restrict__ Kout, float* __restrict__ Qout, ushort* __restrict__ msgB)
{
    const int b = blockIdx.x;
    const int tid = threadIdx.x;
    const int lane = tid & 63, w = tid >> 6;
    const int l15 = lane & 15, lq = lane >> 4;

    __shared__ ushort nimTh[80 * 136];        // [m*16+N][e] pitch 136 (2-way free)
    __shared__ ushort nimTl[80 * 136];
    __shared__ ushort planes[4 * 32 * 104];   // Ykh|Ykl|Yqh|Yql ; later xM[128][104]

    ushort* Ykh = planes;
    ushort* Ykl = planes + 32 * 104;
    ushort* Yqh = planes + 2 * 32 * 104;
    ushort* Yql = planes + 3 * 32 * 104;

    // one-time zeroing: nimT rows m*16+15; planes pad cols [75,104) (all 4 planes
    // via the flat [128][104] view; Y/msg writes only touch cols < 75)
    for (int t = tid; t < 5 * 136; t += 512) {
        int mm = t / 136, e = t - mm * 136;
        nimTh[(mm * 16 + 15) * 136 + e] = 0;
        nimTl[(mm * 16 + 15) * 136 + e] = 0;
    }
    for (int t = tid; t < 128 * 29; t += 512) {
        int r = t / 29, cc = 75 + (t - r * 29);
        planes[r * 104 + cc] = 0;
    }

    const f32x4 zz = {0.f, 0.f, 0.f, 0.f};

    // ---- phase 0: nimT (split x split, 3 passes), no inner barriers ----
    {
        bf16x8 ah[2], al[2];
        #pragma unroll
        for (int ks = 0; ks < 2; ++ks) {
            const float* np = node + (size_t)(w * 16 + l15) * BN + b * 64 + ks * 32 + lq * 8;
            float tmp[8];
            *(float4*)tmp       = *(const float4*)np;
            *(float4*)(tmp + 4) = *(const float4*)(np + 4);
            #pragma unroll
            for (int j = 0; j < 8; ++j) {
                ushort h_, l_; split2(tmp[j], h_, l_);
                ah[ks][j] = (short)h_; al[ks][j] = (short)l_;
            }
        }
        for (int m = 0; m < Mm; ++m) {
            const float* wp = WW + ((size_t)b * Mm + m) * 960 + (l15 < 15 ? l15 : 0);
            f32x4 c = zz;
            #pragma unroll
            for (int ks = 0; ks < 2; ++ks) {
                bf16x8 bh, bl;
                #pragma unroll
                for (int t = 0; t < 8; ++t) {
                    int n = ks * 32 + lq * 8 + t;
                    float v = (l15 < 15) ? wp[n * 15] : 0.f;
                    ushort h_, l_; split2(v, h_, l_);
                    bh[t] = (short)h_; bl[t] = (short)l_;
                }
                c = MFMA(ah[ks], bh, c); c = MFMA(ah[ks], bl, c); c = MFMA(al[ks], bh, c);
            }
            if (l15 < 15) {
                #pragma unroll
                for (int t = 0; t < 4; ++t) {
                    int e = w * 16 + lq * 4 + t;
                    split2(c[t], nimTh[(m * 16 + l15) * 136 + e],
                                 nimTl[(m * 16 + l15) * 136 + e]);
                }
            }
        }
    }
    __syncthreads();

    // ---- 4 quarters: fused K+Q Y-phase then mask-phase ----
    for (int qd = 0; qd < 4; ++qd) {
        for (int u = w; u < 10; u += 8) {
            int m = u >> 1, rt = u & 1;
            int d0 = qd * 32 + rt * 16 + l15;
            f32x4 cK = zz, cQ = zz;
            #pragma unroll
            for (int ks = 0; ks < 4; ++ks) {
                int k0 = ks * 32 + lq * 8;
                size_t wo = (size_t)m * 16384 + (size_t)d0 * 128 + k0;
                bf16x8 kh = *(const bf16x8*)(WKhi + wo);
                bf16x8 kl = *(const bf16x8*)(WKlo + wo);
                bf16x8 qh = *(const bf16x8*)(WQhi + wo);
                bf16x8 ql = *(const bf16x8*)(WQlo + wo);
                bf16x8 bh = *(const bf16x8*)(&nimTh[(m * 16 + l15) * 136 + k0]);
                bf16x8 bl = *(const bf16x8*)(&nimTl[(m * 16 + l15) * 136 + k0]);
                cK = MFMA(kh, bh, cK); cK = MFMA(kh, bl, cK); cK = MFMA(kl, bh, cK);
                cQ = MFMA(qh, bh, cQ); cQ = MFMA(qh, bl, cQ); cQ = MFMA(ql, bh, cQ);
            }
            if (l15 < 15) {
                int j = m * 15 + l15;
                #pragma unroll
                for (int t = 0; t < 4; ++t) {
                    int r = rt * 16 + lq * 4 + t;
                    split2(cK[t], Ykh[r * 104 + j], Ykl[r * 104 + j]);
                    split2(cQ[t], Yqh[r * 104 + j], Yql[r * 104 + j]);
                }
            }
        }
        __syncthreads();
        {
            int rt = w >> 2, ct = w & 3;
            bf16x8 mh[3], ml[3];
            #pragma unroll
            for (int ks = 0; ks < 3; ++ks) {
                int k0 = ks * 32 + lq * 8;
                mh[ks] = *(const bf16x8*)(maskThi + (ct * 16 + l15) * 96 + k0);
                ml[ks] = *(const bf16x8*)(maskTlo + (ct * 16 + l15) * 96 + k0);
            }
            f32x4 cK = zz, cQ = zz;
            #pragma unroll
            for (int ks = 0; ks < 3; ++ks) {
                int k0 = ks * 32 + lq * 8;
                bf16x8 ah = *(const bf16x8*)(&Ykh[(rt * 16 + l15) * 104 + k0]);
                bf16x8 al = *(const bf16x8*)(&Ykl[(rt * 16 + l15) * 104 + k0]);
                cK = MFMA(ah, mh[ks], cK); cK = MFMA(ah, ml[ks], cK); cK = MFMA(al, mh[ks], cK);
                bf16x8 qa = *(const bf16x8*)(&Yqh[(rt * 16 + l15) * 104 + k0]);
                bf16x8 qb = *(const bf16x8*)(&Yql[(rt * 16 + l15) * 104 + k0]);
                cQ = MFMA(qa, mh[ks], cQ); cQ = MFMA(qa, ml[ks], cQ); cQ = MFMA(qb, mh[ks], cQ);
            }
            #pragma unroll
            for (int t = 0; t < 4; ++t) {
                int d = qd * 32 + rt * 16 + lq * 4 + t;
                int col = ct * 16 + l15;
                size_t gi = (size_t)b * 8192 + (size_t)d * 64 + col;
                Kout[gi] = cK[t] + btK[d * 64 + col];
                Qout[gi] = cQ[t] + btQ[d * 64 + col];
            }
        }
        __syncthreads();
    }

    // ---- msg: Y flat-scatter into planes as xM[128][104] ----
    {
        int rt = w;   // 0..7, A-frag row block fixed per wave
        for (int m = 0; m < Mm; ++m) {
            f32x4 c = zz;
            #pragma unroll
            for (int ks = 0; ks < 4; ++ks) {
                int k0 = ks * 32 + lq * 8;
                bf16x8 a  = *(const bf16x8*)(WMhi + (size_t)m * 16384 + (size_t)(rt * 16 + l15) * 128 + k0);
                bf16x8 bh = *(const bf16x8*)(&nimTh[(m * 16 + l15) * 136 + k0]);
                c = MFMA(a, bh, c);
            }
            if (l15 < 15) {
                #pragma unroll
                for (int t = 0; t < 4; ++t) {
                    int d = rt * 16 + lq * 4 + t;
                    int g = m * 1920 + d * 15 + l15;
                    planes[(g / 75) * 104 + (g % 75)] = f2bf(c[t]);
                }
            }
        }
    }
    __syncthreads();
    // ---- msg: mask GEMM (single bf16) ----
    #pragma unroll
    for (int s = 0; s < 4; ++s) {
        int u = w * 4 + s;
        int rt = u & 7, ct = u >> 3;
        f32x4 c = zz;
        #pragma unroll
        for (int ks = 0; ks < 3; ++ks) {
            int k0 = ks * 32 + lq * 8;
            bf16x8 a  = *(const bf16x8*)(&planes[(rt * 16 + l15) * 104 + k0]);
            bf16x8 bh = *(const bf16x8*)(maskThi + (ct * 16 + l15) * 96 + k0);
            c = MFMA(a, bh, c);
        }
        #pragma unroll
        for (int t = 0; t < 4; ++t) {
            int dd = rt * 16 + lq * 4 + t;
            int col = ct * 16 + l15;
            msgB[(size_t)b * 8192 + dd * 64 + col] = f2bf(c[t] + btM[dd * 64 + col]);
        }
    }
}

// ---------------------------------------------------------------------------
// k2 (unchanged from round 3/4): per (b,h), MFMA everywhere.
// ---------------------------------------------------------------------------
__global__ __launch_bounds__(512, 4) void k2_attn(
    const float* __restrict__ Kd, const float* __restrict__ Qd,
    ushort* msgB,  // read msg, write B (same slice per block)
    const float* __restrict__ R, const float* __restrict__ am,
    const ushort* __restrict__ WcatT, float* __restrict__ aw00)
{
    const int b = blockIdx.x >> 2, h = blockIdx.x & 3;
    const int tid = threadIdx.x;
    const int lane = tid & 63, w = tid >> 6;
    const int l15 = lane & 15, lq = lane >> 4;

    __shared__ ushort QTh[64 * 40], QTl[64 * 40];
    __shared__ ushort KTh[64 * 40], KTl[64 * 40];
    __shared__ ushort msgT[64 * 40];
    __shared__ float  ST[64 * 65];
    __shared__ ushort resS[128 * 72];
    __shared__ ushort awq[64 * 72];

    const size_t base = (size_t)b * 8192 + h * 2048;
    for (int i = tid; i < 2048; i += 512) {
        int d = i >> 6, n = i & 63;
        ushort hi, lo;
        split2(Qd[base + i], hi, lo); QTh[n * 40 + d] = hi; QTl[n * 40 + d] = lo;
        split2(Kd[base + i], hi, lo); KTh[n * 40 + d] = hi; KTl[n * 40 + d] = lo;
        msgT[n * 40 + d] = msgB[base + i];
    }
    __syncthreads();

    const float* Rb = R + ((size_t)b * Hh + h) * 4096;
    {
        int ti = w >> 1;
        bf16x8 ah = *reinterpret_cast<const bf16x8*>(&QTh[(ti * 16 + l15) * 40 + lq * 8]);
        bf16x8 al = *reinterpret_cast<const bf16x8*>(&QTl[(ti * 16 + l15) * 40 + lq * 8]);
        #pragma unroll
        for (int s = 0; s < 2; ++s) {
            int tj = (w & 1) * 2 + s;
            bf16x8 bh = *reinterpret_cast<const bf16x8*>(&KTh[(tj * 16 + l15) * 40 + lq * 8]);
            bf16x8 bl = *reinterpret_cast<const bf16x8*>(&KTl[(tj * 16 + l15) * 40 + lq * 8]);
            f32x4 c = {0.f, 0.f, 0.f, 0.f};
            c = MFMA(ah, bh, c); c = MFMA(ah, bl, c); c = MFMA(al, bh, c);
            #pragma unroll
            for (int r = 0; r < 4; ++r) {
                int i = ti * 16 + lq * 4 + r, j = tj * 16 + l15;
                ST[j * 65 + i] = Rb[i * 64 + j] + c[r] * RSQRT_DK;
            }
        }
    }
    {
        bf16x8 a = *reinterpret_cast<const bf16x8*>(WcatT + (w * 16 + l15) * 32 + lq * 8);
        #pragma unroll
        for (int nt = 0; nt < 4; ++nt) {
            bf16x8 bfr = *reinterpret_cast<const bf16x8*>(&msgT[(nt * 16 + l15) * 40 + lq * 8]);
            f32x4 c = {0.f, 0.f, 0.f, 0.f};
            c = MFMA(a, bfr, c);
            #pragma unroll
            for (int r = 0; r < 4; ++r)
                resS[(w * 16 + lq * 4 + r) * 72 + nt * 16 + l15] = f2bf(c[r]);
        }
    }
    __syncthreads();

    {
        int row = tid >> 3, part = tid & 7;
        float v[8]; float mx = -INFINITY;
        #pragma unroll
        for (int jj = 0; jj < 8; ++jj) { v[jj] = ST[(part * 8 + jj) * 65 + row]; mx = fmaxf(mx, v[jj]); }
        mx = fmaxf(mx, __shfl_xor(mx, 1));
        mx = fmaxf(mx, __shfl_xor(mx, 2));
        mx = fmaxf(mx, __shfl_xor(mx, 4));
        float s = 0.f;
        #pragma unroll
        for (int jj = 0; jj < 8; ++jj) { v[jj] = expf(v[jj] - mx); s += v[jj]; }
        s += __shfl_xor(s, 1); s += __shfl_xor(s, 2); s += __shfl_xor(s, 4);
        float inv = 1.f / s;
        #pragma unroll
        for (int jj = 0; jj < 8; ++jj) {
            float p = v[jj] * inv;
            ST[(part * 8 + jj) * 65 + row] = isnan(p) ? 0.f : p;
        }
    }
    __syncthreads();

    const int kt = w >> 2, it = w & 3;
    f32x4 accB = {0.f, 0.f, 0.f, 0.f};
    for (int q = 0; q < 4; ++q) {
        for (int e = tid; e < 4096; e += 512) {
            int i = e >> 6, j0 = e & 63;
            float p = ST[j0 * 65 + i] * am[i * 256 + q * 64 + j0];
            awq[i * 72 + j0] = f2bf(p);
            if (blockIdx.x == 0) aw00[i * 256 + q * 64 + j0] = p;
        }
        __syncthreads();
        #pragma unroll
        for (int ks = 0; ks < 2; ++ks) {
            int row = 4 * (kt * 16 + l15) + q;
            bf16x8 a   = *reinterpret_cast<const bf16x8*>(&resS[row * 72 + ks * 32 + lq * 8]);
            bf16x8 bfr = *reinterpret_cast<const bf16x8*>(&awq[(it * 16 + l15) * 72 + ks * 32 + lq * 8]);
            accB = MFMA(a, bfr, accB);
        }
        __syncthreads();
    }

    #pragma unroll
    for (int r = 0; r < 4; ++r) {
        int k = kt * 16 + lq * 4 + r, i = it * 16 + l15;
        float x = accB[r];
        float g = 0.5f * x * (1.f + erff(x * 0.70710678118654752f));
        msgB[base + k * 64 + i] = f2bf(g);
    }
}

// ---------------------------------------------------------------------------
// k3 (unchanged from round 3/4): per-b output projection + residual.
// ---------------------------------------------------------------------------
__global__ __launch_bounds__(512, 4) void k3_out(
    const ushort* __restrict__ Bbuf, const float* __restrict__ WW,
    const ushort* __restrict__ WBhi, const ushort* __restrict__ maskhi,
    const float* __restrict__ btB, const float* __restrict__ node,
    float* __restrict__ outp)
{
    const int b = blockIdx.x, tid = threadIdx.x;
    const int lane = tid & 63, w = tid >> 6, l15 = lane & 15, lq = lane >> 4;
    __shared__ ushort sB[128 * 66];
    __shared__ ushort wwh[64 * 17];
    __shared__ ushort t1[128 * 17];
    __shared__ ushort nm[32 * 66];

    for (int i = tid; i < 8192; i += 512) {
        int d = i >> 6, n = i & 63;
        sB[d * 66 + n] = Bbuf[(size_t)b * 8192 + i];
    }
    const f32x4 zz = {0.f, 0.f, 0.f, 0.f};
    f32x4 acc[4];
    for (int c = 0; c < 4; ++c) acc[c] = zz;
    __syncthreads();

    for (int m = 0; m < Mm; ++m) {
        for (int i = tid; i < 64 * 17; i += 512) {
            int n = i / 17, N = i - n * 17;
            wwh[i] = (N < 15) ? f2bf(WW[(((size_t)b * Mm + m) * 64 + n) * 15 + N]) : (ushort)0;
        }
        __syncthreads();
        {
            f32x4 c = zz;
            for (int ks = 0; ks < 2; ++ks) {
                int k0 = ks * 32 + (lq << 3);
                bf16x8 a, bh;
                #pragma unroll
                for (int t = 0; t < 8; ++t) {
                    a[t] = (short)sB[(w * 16 + l15) * 66 + k0 + t];
                    bh[t] = (short)wwh[(k0 + t) * 17 + l15];
                }
                c = MFMA(a, bh, c);
            }
            #pragma unroll
            for (int t = 0; t < 4; ++t)
                t1[(w * 16 + lq * 4 + t) * 17 + l15] = f2bf(c[t]);
        }
        __syncthreads();

        bf16x8 mfh;
        {
            int ct = w & 3;
            int k0 = lq << 3;
            #pragma unroll
            for (int t = 0; t < 8; ++t) {
                int kk = k0 + t;
                int row = (kk < 15) ? (m * 15 + kk) : 95;
                mfh[t] = (short)maskhi[row * 64 + ct * 16 + l15];
            }
        }
        for (int eb = 0; eb < 4; ++eb) {
            {
                int rtl = w >> 2, ct = w & 3;
                int e = eb * 32 + rtl * 16 + l15;
                int k0 = lq << 3;
                bf16x8 a;
                #pragma unroll
                for (int t = 0; t < 8; ++t) {
                    int kk = k0 + t;
                    int cc = (kk < 15) ? kk : 15;
                    a[t] = (short)t1[e * 17 + cc];
                }
                f32x4 c = zz;
                c = MFMA(a, mfh, c);
                #pragma unroll
                for (int t = 0; t < 4; ++t)
                    nm[(rtl * 16 + lq * 4 + t) * 66 + ct * 16 + l15] = f2bf(c[t]);
            }
            __syncthreads();
            {
                size_t aoff = (size_t)(w * 16 + l15) * 128 + eb * 32 + (lq << 3);
                bf16x8 a = *reinterpret_cast<const bf16x8*>(WBhi + m * 16384 + aoff);
                int k0 = lq << 3;
                #pragma unroll
                for (int ct = 0; ct < 4; ++ct) {
                    bf16x8 bh;
                    #pragma unroll
                    for (int t = 0; t < 8; ++t) bh[t] = (short)nm[(k0 + t) * 66 + ct * 16 + l15];
                    acc[ct] = MFMA(a, bh, acc[ct]);
                }
            }
            __syncthreads();
        }
    }
    #pragma unroll
    for (int ct = 0; ct < 4; ++ct) {
        #pragma unroll
        for (int t = 0; t < 4; ++t) {
            int d = w * 16 + lq * 4 + t;
            int col = ct * 16 + l15;
            size_t gi = (size_t)d * BN + b * 64 + col;
            outp[gi] = acc[ct][t] + btB[d * 64 + col] + node[gi];
        }
    }
}

extern "C" void kernel_launch(void* const* d_in, const int* in_sizes, int n_in,
                              void* d_out, int out_size, void* d_ws, size_t ws_size,
                              hipStream_t stream) {
    const float* node  = (const float*)d_in[0];
    const float* WW    = (const float*)d_in[1];
    const float* maskm = (const float*)d_in[2];
    const float* R     = (const float*)d_in[3];
    const float* am    = (const float*)d_in[4];
    const float* WK = (const float*)d_in[5];  const float* bK = (const float*)d_in[6];
    const float* WQ = (const float*)d_in[7];  const float* bQ = (const float*)d_in[8];
    const float* WM = (const float*)d_in[9];  const float* bM = (const float*)d_in[10];
    const float* WB = (const float*)d_in[11]; const float* bB = (const float*)d_in[12];
    const float* Wu = (const float*)d_in[13]; const float* Wd = (const float*)d_in[14];
    const float* Wl = (const float*)d_in[15]; const float* Wr = (const float*)d_in[16];

    float* out  = (float*)d_out;                 // K staging, then final out
    float* aw00 = out + (size_t)Dd * BN;         // disjoint tail of d_out

    char* W = (char*)d_ws;
    float*  Qbuf   = (float*)W;                          // 33,554,432 B
    ushort* msgB   = (ushort*)(W + 33554432);            // 16,777,216 B (msg, then B)
    ushort* WKhi   = (ushort*)(W + 50331648);
    ushort* WKlo   = WKhi + 81920;
    ushort* WQhi   = WKlo + 81920;
    ushort* WQlo   = WQhi + 81920;
    ushort* WMhi   = WQlo + 81920;
    ushort* WBhi   = WMhi + 81920;
    ushort* maskhi = WBhi + 81920;                       // 96*64 row-major
    ushort* masklo = maskhi + 6144;
    float*  btK    = (float*)(masklo + 6144);
    float*  btQ    = btK + 8192;
    float*  btM    = btQ + 8192;
    float*  btB    = btM + 8192;
    ushort* WcatT  = (ushort*)(btB + 8192);              // [128][32]
    ushort* maskThi = WcatT + 4096;                      // [64][96] transposed
    ushort* maskTlo = maskThi + 6144;

    k0_prep<<<512, 256, 0, stream>>>(maskm, WK, bK, WQ, bQ, WM, bM, WB, bB,
                                     Wu, Wd, Wl, Wr,
                                     WKhi, WKlo, WQhi, WQlo, WMhi, WBhi,
                                     maskhi, masklo, maskThi, maskTlo,
                                     btK, btQ, btM, btB, WcatT);
    k1_proj<<<Bb, 512, 0, stream>>>(node, WW, WKhi, WKlo, WQhi, WQlo, WMhi,
                                    maskThi, maskTlo, btK, btQ, btM,
                                    out, Qbuf, msgB);
    k2_attn<<<Bb * Hh, 512, 0, stream>>>(out, Qbuf, msgB, R, am, WcatT, aw00);
    k3_out<<<Bb, 512, 0, stream>>>(msgB, WW, WBhi, maskhi, btB, node, out);
}

// Round 6
// 279.675 us; speedup vs baseline: 1.0635x; 1.0635x over previous
//
#include <hip/hip_runtime.h>
#include <math.h>

#define Dd 128
#define Hh 4
#define DKk 32
#define Mm 5
#define NNn 15
#define Bb 1024
#define Nn 64
#define MN 75
#define BN 65536
#define RSQRT_DK 0.17677669529663687f

typedef __attribute__((ext_vector_type(8))) short bf16x8;
typedef __attribute__((ext_vector_type(4))) float f32x4;

__device__ __forceinline__ ushort f2bf(float x) {
    unsigned u = __float_as_uint(x);
    u = (u + 0x7fffu + ((u >> 16) & 1u)) >> 16;
    return (ushort)u;
}
__device__ __forceinline__ float bf2f(ushort h) {
    return __uint_as_float(((unsigned)h) << 16);
}
__device__ __forceinline__ void split2(float x, ushort& hi, ushort& lo) {
    hi = f2bf(x);
    lo = f2bf(x - bf2f(hi));
}
__device__ __forceinline__ f32x4 MFMA(bf16x8 a, bf16x8 b, f32x4 c) {
    return __builtin_amdgcn_mfma_f32_16x16x32_bf16(a, b, c, 0, 0, 0);
}

// ---------------------------------------------------------------------------
// k0: weight preprocessing (tiny, every call).
//  - WK/WQ split hi/lo; WM/WB hi
//  - maskhi/lo row-major [96][64] (k3); maskThi/lo transposed [64][96] (k1)
//  - btKT/btQT/btMT transposed [n][d] (k1 transposed stores); btB row-major (k3)
//  - WcatT (k2)
// ---------------------------------------------------------------------------
__global__ void k0_prep(const float* __restrict__ maskm,
                        const float* __restrict__ WK, const float* __restrict__ bK,
                        const float* __restrict__ WQ, const float* __restrict__ bQ,
                        const float* __restrict__ WM, const float* __restrict__ bM,
                        const float* __restrict__ WB, const float* __restrict__ bB,
                        const float* __restrict__ Wu, const float* __restrict__ Wd,
                        const float* __restrict__ Wl, const float* __restrict__ Wr,
                        ushort* __restrict__ WKhi, ushort* __restrict__ WKlo,
                        ushort* __restrict__ WQhi, ushort* __restrict__ WQlo,
                        ushort* __restrict__ WMhi, ushort* __restrict__ WBhi,
                        ushort* __restrict__ maskhi, ushort* __restrict__ masklo,
                        ushort* __restrict__ maskThi, ushort* __restrict__ maskTlo,
                        float* __restrict__ btKT, float* __restrict__ btQT,
                        float* __restrict__ btMT, float* __restrict__ btB,
                        ushort* __restrict__ WcatT)
{
    int tid = blockIdx.x * blockDim.x + threadIdx.x;
    int nthr = gridDim.x * blockDim.x;
    const int NW = Mm * Dd * Dd;  // 81920
    for (int i = tid; i < NW; i += nthr) {
        split2(WK[i], WKhi[i], WKlo[i]);
        split2(WQ[i], WQhi[i], WQlo[i]);
        WMhi[i] = f2bf(WM[i]);
        WBhi[i] = f2bf(WB[i]);
    }
    for (int i = tid; i < 96 * 64; i += nthr) {
        float v = (i < MN * 64) ? maskm[i] : 0.f;
        split2(v, maskhi[i], masklo[i]);
    }
    for (int i = tid; i < 64 * 96; i += nthr) {
        int col = i / 96, j = i - col * 96;
        float v = (j < MN) ? maskm[j * 64 + col] : 0.f;
        split2(v, maskThi[i], maskTlo[i]);
    }
    for (int i = tid; i < 4096; i += nthr) {
        int q = i >> 5, kk = i & 31;
        const float* Wsel = (q < 32) ? Wu : (q < 64) ? Wd : (q < 96) ? Wl : Wr;
        WcatT[i] = f2bf(Wsel[kk * 32 + (q & 31)]);
    }
    for (int i = tid; i < 8192; i += nthr) {
        int d = i >> 6, col = i & 63;
        float aKv = 0.f, aQv = 0.f, aBv = 0.f;
        for (int m = 0; m < Mm; ++m) {
            float mrs = 0.f;
            for (int N = 0; N < NNn; ++N) mrs += maskm[(m * 15 + N) * 64 + col];
            aKv += bK[m * 128 + d] * mrs;
            aQv += bQ[m * 128 + d] * mrs;
            aBv += bB[m * 128 + d] * mrs;
        }
        btKT[col * 128 + d] = aKv;
        btQT[col * 128 + d] = aQv;
        btB[i] = aBv;
        float aMv = 0.f;
        for (int j = 0; j < MN; ++j) {
            int f = d * 75 + j;
            int m = f / 1920;
            int dloc = (f / 15) & 127;
            aMv += bM[m * 128 + dloc] * maskm[j * 64 + col];
        }
        btMT[col * 128 + d] = aMv;
    }
}

// ---------------------------------------------------------------------------
// k1 v6: ILP-split accumulators + swapped mask-GEMMs with transposed-split
// K/Q/msg outputs in k2's native [b][h][n][dk] layout.
// ---------------------------------------------------------------------------
__global__ __launch_bounds__(512, 4) void k1_proj(
    const float* __restrict__ node, const float* __restrict__ WW,
    const ushort* __restrict__ WKhi, const ushort* __restrict__ WKlo,
    const ushort* __restrict__ WQhi, const ushort* __restrict__ WQlo,
    const ushort* __restrict__ WMhi,
    const ushort* __restrict__ maskThi, const ushort* __restrict__ maskTlo,
    const float* __restrict__ btKT, const float* __restrict__ btQT,
    const float* __restrict__ btMT,
    ushort* __restrict__ Khi, ushort* __restrict__ Klo,
    ushort* __restrict__ Qhi, ushort* __restrict__ Qlo,
    ushort* __restrict__ msgTg)
{
    const int b = blockIdx.x;
    const int tid = threadIdx.x;
    const int lane = tid & 63, w = tid >> 6;
    const int l15 = lane & 15, lq = lane >> 4;

    __shared__ ushort nimTh[80 * 136];        // [m*16+N][e] pitch 136
    __shared__ ushort nimTl[80 * 136];
    __shared__ ushort planes[4 * 32 * 104];   // Ykh|Ykl|Yqh|Yql ; later xM[128][104]

    ushort* Ykh = planes;
    ushort* Ykl = planes + 32 * 104;
    ushort* Yqh = planes + 2 * 32 * 104;
    ushort* Yql = planes + 3 * 32 * 104;

    for (int t = tid; t < 5 * 136; t += 512) {
        int mm = t / 136, e = t - mm * 136;
        nimTh[(mm * 16 + 15) * 136 + e] = 0;
        nimTl[(mm * 16 + 15) * 136 + e] = 0;
    }
    for (int t = tid; t < 128 * 29; t += 512) {
        int r = t / 29, cc = 75 + (t - r * 29);
        planes[r * 104 + cc] = 0;
    }

    const f32x4 zz = {0.f, 0.f, 0.f, 0.f};

    // ---- phase 0: nimT, 3 independent split-product chains ----
    {
        bf16x8 ah[2], al[2];
        #pragma unroll
        for (int ks = 0; ks < 2; ++ks) {
            const float* np = node + (size_t)(w * 16 + l15) * BN + b * 64 + ks * 32 + lq * 8;
            float tmp[8];
            *(float4*)tmp       = *(const float4*)np;
            *(float4*)(tmp + 4) = *(const float4*)(np + 4);
            #pragma unroll
            for (int j = 0; j < 8; ++j) {
                ushort h_, l_; split2(tmp[j], h_, l_);
                ah[ks][j] = (short)h_; al[ks][j] = (short)l_;
            }
        }
        for (int m = 0; m < Mm; ++m) {
            const float* wp = WW + ((size_t)b * Mm + m) * 960 + (l15 < 15 ? l15 : 0);
            f32x4 chh = zz, chl = zz, clh = zz;
            #pragma unroll
            for (int ks = 0; ks < 2; ++ks) {
                bf16x8 bh, bl;
                #pragma unroll
                for (int t = 0; t < 8; ++t) {
                    int n = ks * 32 + lq * 8 + t;
                    float v = (l15 < 15) ? wp[n * 15] : 0.f;
                    ushort h_, l_; split2(v, h_, l_);
                    bh[t] = (short)h_; bl[t] = (short)l_;
                }
                chh = MFMA(ah[ks], bh, chh);
                chl = MFMA(ah[ks], bl, chl);
                clh = MFMA(al[ks], bh, clh);
            }
            f32x4 c = chh + chl + clh;
            if (l15 < 15) {
                #pragma unroll
                for (int t = 0; t < 4; ++t) {
                    int e = w * 16 + lq * 4 + t;
                    split2(c[t], nimTh[(m * 16 + l15) * 136 + e],
                                 nimTl[(m * 16 + l15) * 136 + e]);
                }
            }
        }
    }
    __syncthreads();

    // ---- 4 quarters: Y-phase (6 chains) then swapped mask-phase (6 chains) ----
    for (int qd = 0; qd < 4; ++qd) {
        for (int u = w; u < 10; u += 8) {
            int m = u >> 1, rt = u & 1;
            int d0 = qd * 32 + rt * 16 + l15;
            f32x4 khh = zz, khl = zz, klh = zz;
            f32x4 qhh = zz, qhl = zz, qlh = zz;
            #pragma unroll
            for (int ks = 0; ks < 4; ++ks) {
                int k0 = ks * 32 + lq * 8;
                size_t wo = (size_t)m * 16384 + (size_t)d0 * 128 + k0;
                bf16x8 akh = *(const bf16x8*)(WKhi + wo);
                bf16x8 akl = *(const bf16x8*)(WKlo + wo);
                bf16x8 aqh = *(const bf16x8*)(WQhi + wo);
                bf16x8 aql = *(const bf16x8*)(WQlo + wo);
                bf16x8 bh = *(const bf16x8*)(&nimTh[(m * 16 + l15) * 136 + k0]);
                bf16x8 bl = *(const bf16x8*)(&nimTl[(m * 16 + l15) * 136 + k0]);
                khh = MFMA(akh, bh, khh); khl = MFMA(akh, bl, khl); klh = MFMA(akl, bh, klh);
                qhh = MFMA(aqh, bh, qhh); qhl = MFMA(aqh, bl, qhl); qlh = MFMA(aql, bh, qlh);
            }
            f32x4 cK = khh + khl + klh;
            f32x4 cQ = qhh + qhl + qlh;
            if (l15 < 15) {
                int j = m * 15 + l15;
                #pragma unroll
                for (int t = 0; t < 4; ++t) {
                    int r = rt * 16 + lq * 4 + t;
                    split2(cK[t], Ykh[r * 104 + j], Ykl[r * 104 + j]);
                    split2(cQ[t], Yqh[r * 104 + j], Yql[r * 104 + j]);
                }
            }
        }
        __syncthreads();
        {
            // swapped: A = maskT (rows n), B = Y (rows d-local) -> C[n][dloc]
            int nr = w & 3, dc = w >> 2;
            f32x4 khh = zz, khl = zz, klh = zz;
            f32x4 qhh = zz, qhl = zz, qlh = zz;
            #pragma unroll
            for (int ks = 0; ks < 3; ++ks) {
                int k0 = ks * 32 + lq * 8;
                bf16x8 mh = *(const bf16x8*)(maskThi + (nr * 16 + l15) * 96 + k0);
                bf16x8 ml = *(const bf16x8*)(maskTlo + (nr * 16 + l15) * 96 + k0);
                bf16x8 ykh = *(const bf16x8*)(&Ykh[(dc * 16 + l15) * 104 + k0]);
                bf16x8 ykl = *(const bf16x8*)(&Ykl[(dc * 16 + l15) * 104 + k0]);
                bf16x8 yqh = *(const bf16x8*)(&Yqh[(dc * 16 + l15) * 104 + k0]);
                bf16x8 yql = *(const bf16x8*)(&Yql[(dc * 16 + l15) * 104 + k0]);
                khh = MFMA(mh, ykh, khh); khl = MFMA(ml, ykh, khl); klh = MFMA(mh, ykl, klh);
                qhh = MFMA(mh, yqh, qhh); qhl = MFMA(ml, yqh, qhl); qlh = MFMA(mh, yql, qlh);
            }
            f32x4 cK = khh + khl + klh;
            f32x4 cQ = qhh + qhl + qlh;
            #pragma unroll
            for (int t = 0; t < 4; ++t) {
                int n = nr * 16 + lq * 4 + t;
                int dloc = dc * 16 + l15;
                int d = qd * 32 + dloc;
                size_t oi = (((size_t)(b * 4 + qd)) * 64 + n) * 32 + dloc;
                ushort hh_, ll_;
                split2(cK[t] + btKT[n * 128 + d], hh_, ll_);
                Khi[oi] = hh_; Klo[oi] = ll_;
                split2(cQ[t] + btQT[n * 128 + d], hh_, ll_);
                Qhi[oi] = hh_; Qlo[oi] = ll_;
            }
        }
        __syncthreads();
    }

    // ---- msg scatter: xM flat (2 chains) ----
    {
        int rt = w;
        for (int m = 0; m < Mm; ++m) {
            f32x4 c0 = zz, c1 = zz;
            #pragma unroll
            for (int ks = 0; ks < 4; ++ks) {
                int k0 = ks * 32 + lq * 8;
                bf16x8 a  = *(const bf16x8*)(WMhi + (size_t)m * 16384 + (size_t)(rt * 16 + l15) * 128 + k0);
                bf16x8 bh = *(const bf16x8*)(&nimTh[(m * 16 + l15) * 136 + k0]);
                if (ks < 2) c0 = MFMA(a, bh, c0); else c1 = MFMA(a, bh, c1);
            }
            f32x4 c = c0 + c1;
            if (l15 < 15) {
                #pragma unroll
                for (int t = 0; t < 4; ++t) {
                    int dflat = rt * 16 + lq * 4 + t;
                    int g = m * 1920 + dflat * 15 + l15;
                    planes[(g / 75) * 104 + (g % 75)] = f2bf(c[t]);
                }
            }
        }
    }
    __syncthreads();
    // ---- msg mask (swapped, single bf16, 3 chains) ----
    #pragma unroll
    for (int s = 0; s < 4; ++s) {
        int u = w * 4 + s;
        int nr = u & 3, ddc = u >> 2;
        f32x4 cs0 = zz, cs1 = zz, cs2 = zz;
        {
            bf16x8 a0 = *(const bf16x8*)(maskThi + (nr * 16 + l15) * 96 + lq * 8);
            bf16x8 b0 = *(const bf16x8*)(&planes[(ddc * 16 + l15) * 104 + lq * 8]);
            cs0 = MFMA(a0, b0, cs0);
            bf16x8 a1 = *(const bf16x8*)(maskThi + (nr * 16 + l15) * 96 + 32 + lq * 8);
            bf16x8 b1 = *(const bf16x8*)(&planes[(ddc * 16 + l15) * 104 + 32 + lq * 8]);
            cs1 = MFMA(a1, b1, cs1);
            bf16x8 a2 = *(const bf16x8*)(maskThi + (nr * 16 + l15) * 96 + 64 + lq * 8);
            bf16x8 b2 = *(const bf16x8*)(&planes[(ddc * 16 + l15) * 104 + 64 + lq * 8]);
            cs2 = MFMA(a2, b2, cs2);
        }
        f32x4 c = cs0 + cs1 + cs2;
        #pragma unroll
        for (int t = 0; t < 4; ++t) {
            int n = nr * 16 + lq * 4 + t;
            int dd = ddc * 16 + l15;
            int h = dd >> 5, dk = dd & 31;
            msgTg[(((size_t)(b * 4 + h)) * 64 + n) * 32 + dk] = f2bf(c[t] + btMT[n * 128 + dd]);
        }
    }
}

// ---------------------------------------------------------------------------
// k2 v6: global-direct fragments (no staging LDS), 44.3KB LDS -> 3 blocks/CU.
// B output overlays the Qhi slice of this block (read-then-write, same thread).
// ---------------------------------------------------------------------------
__global__ __launch_bounds__(512, 4) void k2_attn(
    const ushort* __restrict__ Khi, const ushort* __restrict__ Klo,
    const ushort* Qhi, const ushort* __restrict__ Qlo,
    const ushort* __restrict__ msgTg,
    const float* __restrict__ R, const float* __restrict__ am,
    const ushort* __restrict__ WcatT, float* __restrict__ aw00,
    ushort* Bout)
{
    const int b = blockIdx.x >> 2, h = blockIdx.x & 3;
    const int tid = threadIdx.x;
    const int lane = tid & 63, w = tid >> 6;
    const int l15 = lane & 15, lq = lane >> 4;

    __shared__ float  ST[64 * 65];
    __shared__ ushort resS[128 * 72];
    __shared__ ushort awq[64 * 72];

    const f32x4 zz = {0.f, 0.f, 0.f, 0.f};
    const size_t base2 = (size_t)(b * 4 + h) * 2048;
    const float* Rb = R + (size_t)(b * 4 + h) * 4096;

    // S = QtK (split, 3 chains per tile)
    {
        int ti = w >> 1;
        bf16x8 ah = *(const bf16x8*)(Qhi + base2 + (size_t)(ti * 16 + l15) * 32 + lq * 8);
        bf16x8 al = *(const bf16x8*)(Qlo + base2 + (size_t)(ti * 16 + l15) * 32 + lq * 8);
        #pragma unroll
        for (int s = 0; s < 2; ++s) {
            int tj = (w & 1) * 2 + s;
            bf16x8 bh = *(const bf16x8*)(Khi + base2 + (size_t)(tj * 16 + l15) * 32 + lq * 8);
            bf16x8 bl = *(const bf16x8*)(Klo + base2 + (size_t)(tj * 16 + l15) * 32 + lq * 8);
            f32x4 chh = zz, chl = zz, clh = zz;
            chh = MFMA(ah, bh, chh); chl = MFMA(ah, bl, chl); clh = MFMA(al, bh, clh);
            f32x4 c = chh + chl + clh;
            #pragma unroll
            for (int r = 0; r < 4; ++r) {
                int i = ti * 16 + lq * 4 + r, j = tj * 16 + l15;
                ST[j * 65 + i] = Rb[i * 64 + j] + c[r] * RSQRT_DK;
            }
        }
    }
    // res = WcatT @ msg (single bf16, 4 independent tiles)
    {
        bf16x8 a = *(const bf16x8*)(WcatT + (w * 16 + l15) * 32 + lq * 8);
        #pragma unroll
        for (int nt = 0; nt < 4; ++nt) {
            bf16x8 bfr = *(const bf16x8*)(msgTg + base2 + (size_t)(nt * 16 + l15) * 32 + lq * 8);
            f32x4 c = MFMA(a, bfr, zz);
            #pragma unroll
            for (int r = 0; r < 4; ++r)
                resS[(w * 16 + lq * 4 + r) * 72 + nt * 16 + l15] = f2bf(c[r]);
        }
    }
    __syncthreads();

    {   // softmax over j per row i: 8 threads/row
        int row = tid >> 3, part = tid & 7;
        float v[8]; float mx = -INFINITY;
        #pragma unroll
        for (int jj = 0; jj < 8; ++jj) { v[jj] = ST[(part * 8 + jj) * 65 + row]; mx = fmaxf(mx, v[jj]); }
        mx = fmaxf(mx, __shfl_xor(mx, 1));
        mx = fmaxf(mx, __shfl_xor(mx, 2));
        mx = fmaxf(mx, __shfl_xor(mx, 4));
        float s = 0.f;
        #pragma unroll
        for (int jj = 0; jj < 8; ++jj) { v[jj] = expf(v[jj] - mx); s += v[jj]; }
        s += __shfl_xor(s, 1); s += __shfl_xor(s, 2); s += __shfl_xor(s, 4);
        float inv = 1.f / s;
        #pragma unroll
        for (int jj = 0; jj < 8; ++jj) {
            float p = v[jj] * inv;
            ST[(part * 8 + jj) * 65 + row] = isnan(p) ? 0.f : p;
        }
    }
    __syncthreads();

    // B = sum_q res_q @ aw_q^T  (2 independent ks-chains)
    const int kt = w >> 2, it = w & 3;
    f32x4 accB0 = zz, accB1 = zz;
    for (int q = 0; q < 4; ++q) {
        for (int e = tid; e < 4096; e += 512) {
            int i = e >> 6, j0 = e & 63;
            float p = ST[j0 * 65 + i] * am[i * 256 + q * 64 + j0];
            awq[i * 72 + j0] = f2bf(p);
            if (blockIdx.x == 0) aw00[i * 256 + q * 64 + j0] = p;
        }
        __syncthreads();
        int row = 4 * (kt * 16 + l15) + q;
        bf16x8 a0 = *(const bf16x8*)(&resS[row * 72 + lq * 8]);
        bf16x8 b0 = *(const bf16x8*)(&awq[(it * 16 + l15) * 72 + lq * 8]);
        accB0 = MFMA(a0, b0, accB0);
        bf16x8 a1 = *(const bf16x8*)(&resS[row * 72 + 32 + lq * 8]);
        bf16x8 b1 = *(const bf16x8*)(&awq[(it * 16 + l15) * 72 + 32 + lq * 8]);
        accB1 = MFMA(a1, b1, accB1);
        __syncthreads();
    }
    f32x4 accB = accB0 + accB1;

    #pragma unroll
    for (int r = 0; r < 4; ++r) {
        int k = kt * 16 + lq * 4 + r, i = it * 16 + l15;
        float x = accB[r];
        float g = 0.5f * x * (1.f + erff(x * 0.70710678118654752f));
        Bout[base2 + k * 64 + i] = f2bf(g);
    }
}

// ---------------------------------------------------------------------------
// k3: per-b output projection + residual. sB pitch 72 for b128 A-frags;
// t1-GEMM ks-split. Otherwise round-5 structure.
// ---------------------------------------------------------------------------
__global__ __launch_bounds__(512, 4) void k3_out(
    const ushort* Bbuf, const float* __restrict__ WW,
    const ushort* __restrict__ WBhi, const ushort* __restrict__ maskhi,
    const float* __restrict__ btB, const float* __restrict__ node,
    float* __restrict__ outp)
{
    const int b = blockIdx.x, tid = threadIdx.x;
    const int lane = tid & 63, w = tid >> 6, l15 = lane & 15, lq = lane >> 4;
    __shared__ ushort sB[128 * 72];
    __shared__ ushort wwh[64 * 17];
    __shared__ ushort t1[128 * 17];
    __shared__ ushort nm[32 * 66];

    for (int i = tid; i < 8192; i += 512) {
        int d = i >> 6, n = i & 63;
        sB[d * 72 + n] = Bbuf[(size_t)b * 8192 + i];
    }
    const f32x4 zz = {0.f, 0.f, 0.f, 0.f};
    f32x4 acc[4];
    for (int c = 0; c < 4; ++c) acc[c] = zz;
    __syncthreads();

    for (int m = 0; m < Mm; ++m) {
        for (int i = tid; i < 64 * 17; i += 512) {
            int n = i / 17, N = i - n * 17;
            wwh[i] = (N < 15) ? f2bf(WW[(((size_t)b * Mm + m) * 64 + n) * 15 + N]) : (ushort)0;
        }
        __syncthreads();
        {
            f32x4 c0 = zz, c1 = zz;
            #pragma unroll
            for (int ks = 0; ks < 2; ++ks) {
                int k0 = ks * 32 + (lq << 3);
                bf16x8 a = *(const bf16x8*)(&sB[(w * 16 + l15) * 72 + k0]);
                bf16x8 bh;
                #pragma unroll
                for (int t = 0; t < 8; ++t) bh[t] = (short)wwh[(k0 + t) * 17 + l15];
                if (ks == 0) c0 = MFMA(a, bh, c0); else c1 = MFMA(a, bh, c1);
            }
            f32x4 c = c0 + c1;
            #pragma unroll
            for (int t = 0; t < 4; ++t)
                t1[(w * 16 + lq * 4 + t) * 17 + l15] = f2bf(c[t]);
        }
        __syncthreads();

        bf16x8 mfh;
        {
            int ct = w & 3;
            int k0 = lq << 3;
            #pragma unroll
            for (int t = 0; t < 8; ++t) {
                int kk = k0 + t;
                int row = (kk < 15) ? (m * 15 + kk) : 95;
                mfh[t] = (short)maskhi[row * 64 + ct * 16 + l15];
            }
        }
        for (int eb = 0; eb < 4; ++eb) {
            {
                int rtl = w >> 2, ct = w & 3;
                int e = eb * 32 + rtl * 16 + l15;
                int k0 = lq << 3;
                bf16x8 a;
                #pragma unroll
                for (int t = 0; t < 8; ++t) {
                    int kk = k0 + t;
                    int cc = (kk < 15) ? kk : 15;
                    a[t] = (short)t1[e * 17 + cc];
                }
                f32x4 c = zz;
                c = MFMA(a, mfh, c);
                #pragma unroll
                for (int t = 0; t < 4; ++t)
                    nm[(rtl * 16 + lq * 4 + t) * 66 + ct * 16 + l15] = f2bf(c[t]);
            }
            __syncthreads();
            {
                size_t aoff = (size_t)(w * 16 + l15) * 128 + eb * 32 + (lq << 3);
                bf16x8 a = *(const bf16x8*)(WBhi + m * 16384 + aoff);
                int k0 = lq << 3;
                #pragma unroll
                for (int ct = 0; ct < 4; ++ct) {
                    bf16x8 bh;
                    #pragma unroll
                    for (int t = 0; t < 8; ++t) bh[t] = (short)nm[(k0 + t) * 66 + ct * 16 + l15];
                    acc[ct] = MFMA(a, bh, acc[ct]);
                }
            }
            __syncthreads();
        }
    }
    #pragma unroll
    for (int ct = 0; ct < 4; ++ct) {
        #pragma unroll
        for (int t = 0; t < 4; ++t) {
            int d = w * 16 + lq * 4 + t;
            int col = ct * 16 + l15;
            size_t gi = (size_t)d * BN + b * 64 + col;
            outp[gi] = acc[ct][t] + btB[d * 64 + col] + node[gi];
        }
    }
}

extern "C" void kernel_launch(void* const* d_in, const int* in_sizes, int n_in,
                              void* d_out, int out_size, void* d_ws, size_t ws_size,
                              hipStream_t stream) {
    const float* node  = (const float*)d_in[0];
    const float* WW    = (const float*)d_in[1];
    const float* maskm = (const float*)d_in[2];
    const float* R     = (const float*)d_in[3];
    const float* am    = (const float*)d_in[4];
    const float* WK = (const float*)d_in[5];  const float* bK = (const float*)d_in[6];
    const float* WQ = (const float*)d_in[7];  const float* bQ = (const float*)d_in[8];
    const float* WM = (const float*)d_in[9];  const float* bM = (const float*)d_in[10];
    const float* WB = (const float*)d_in[11]; const float* bB = (const float*)d_in[12];
    const float* Wu = (const float*)d_in[13]; const float* Wd = (const float*)d_in[14];
    const float* Wl = (const float*)d_in[15]; const float* Wr = (const float*)d_in[16];

    float* out  = (float*)d_out;
    float* aw00 = out + (size_t)Dd * BN;

    // K split planes exactly fill the out region (dead before k3 writes out)
    ushort* Khi = (ushort*)d_out;
    ushort* Klo = Khi + 8388608;

    char* W = (char*)d_ws;
    ushort* Qhi   = (ushort*)W;                   // 16,777,216 B (also Bout/Bbuf)
    ushort* Qlo   = Qhi + 8388608;                // 16,777,216 B
    ushort* msgTg = Qlo + 8388608;                // 16,777,216 B
    ushort* WKhi  = msgTg + 8388608;
    ushort* WKlo  = WKhi + 81920;
    ushort* WQhi  = WKlo + 81920;
    ushort* WQlo  = WQhi + 81920;
    ushort* WMhi  = WQlo + 81920;
    ushort* WBhi  = WMhi + 81920;
    ushort* maskhi  = WBhi + 81920;
    ushort* masklo  = maskhi + 6144;
    ushort* maskThi = masklo + 6144;
    ushort* maskTlo = maskThi + 6144;
    ushort* WcatT   = maskTlo + 6144;
    float*  btKT = (float*)(WcatT + 4096);
    float*  btQT = btKT + 8192;
    float*  btMT = btQT + 8192;
    float*  btB  = btMT + 8192;
    // total ws use ~51.5 MB

    k0_prep<<<512, 256, 0, stream>>>(maskm, WK, bK, WQ, bQ, WM, bM, WB, bB,
                                     Wu, Wd, Wl, Wr,
                                     WKhi, WKlo, WQhi, WQlo, WMhi, WBhi,
                                     maskhi, masklo, maskThi, maskTlo,
                                     btKT, btQT, btMT, btB, WcatT);
    k1_proj<<<Bb, 512, 0, stream>>>(node, WW, WKhi, WKlo, WQhi, WQlo, WMhi,
                                    maskThi, maskTlo, btKT, btQT, btMT,
                                    Khi, Klo, Qhi, Qlo, msgTg);
    k2_attn<<<Bb * Hh, 512, 0, stream>>>(Khi, Klo, Qhi, Qlo, msgTg, R, am,
                                         WcatT, aw00, Qhi /*Bout overlay*/);
    k3_out<<<Bb, 512, 0, stream>>>(Qhi /*Bbuf*/, WW, WBhi, maskhi, btB, node, out);
}